// Round 3
// baseline (14914.355 us; speedup 1.0000x reference)
//
#include <hip/hip_runtime.h>

// EA-LSTM fused kernel, v3: pure fp32 (precision-mandated; f16 recurrence diverges
// in c_n — round 2 absmax 78 vs 2.17), three-tier weight residency.
//
// B=256 blocks, one batch element per block (1 block/CU). 512 threads = 8 waves.
// Stacked weights [W_hh(256); W_ih(32)] = 288 x 768 fp32 = 864 KB: doesn't fit any
// single on-CU store. Split per thread (kq = t>>8 owns K-chunk of 144 rows,
// a = t&255 owns columns {a, a+256, a+512} = f/o/g of h-index a):
//   - rows kbase+ 0..67  : 204 VGPRs/thread (417 KB/CU)
//   - rows kbase+68..91  : LDS, interleaved float4 [18][512] (147 KB, 8-cy b128 reads)
//   - rows kbase+92..143 : streamed from L2 every step (~320 KB/CU/step) — the wall.
// h stays fp32 in LDS (broadcast reads); c-state fp32 in registers.

#define BB 256
#define SS 365
#define FD 32
#define FS 27
#define HH 256
#define G3 768
#define KCH 144          // K rows per kq chunk
#define RV 68            // VGPR-resident rows per thread
#define RL 24            // LDS-resident rows per thread
#define NQS 13           // streamed quad-blocks (52 rows)

#define FMA12(v, h4) do { \
    acc0 = fmaf((v)[0],  (h4).x, acc0); acc1 = fmaf((v)[1],  (h4).x, acc1); acc2 = fmaf((v)[2],  (h4).x, acc2); \
    acc0 = fmaf((v)[3],  (h4).y, acc0); acc1 = fmaf((v)[4],  (h4).y, acc1); acc2 = fmaf((v)[5],  (h4).y, acc2); \
    acc0 = fmaf((v)[6],  (h4).z, acc0); acc1 = fmaf((v)[7],  (h4).z, acc1); acc2 = fmaf((v)[8],  (h4).z, acc2); \
    acc0 = fmaf((v)[9],  (h4).w, acc0); acc1 = fmaf((v)[10], (h4).w, acc1); acc2 = fmaf((v)[11], (h4).w, acc2); \
} while (0)

// Load 4 stacked rows (kst..kst+3) x 3 gate-columns into buf[12]. kst is
// wave-uniform -> the W_hh/W_ih select is a scalar cselect.
#define LOADQ(buf, kst) do { \
    _Pragma("unroll") \
    for (int rr_ = 0; rr_ < 4; ++rr_) { \
        const int k_ = (kst) + rr_; \
        const float* p_ = (k_ < HH) ? (W_hh + (size_t)k_ * G3) \
                                    : (W_ih + (size_t)(k_ - HH) * G3); \
        (buf)[3*rr_+0] = p_[a]; \
        (buf)[3*rr_+1] = p_[a + 256]; \
        (buf)[3*rr_+2] = p_[a + 512]; \
    } \
} while (0)

__device__ __forceinline__ float sigmoidf_(float x) {
    return 1.f / (1.f + __expf(-x));
}
__device__ __forceinline__ float tanhf_(float x) {
    return 1.f - 2.f / (1.f + __expf(2.f * x));   // overflow-safe
}

__global__ __launch_bounds__(512) void ealstm_kernel(
    const float* __restrict__ x_d, const float* __restrict__ x_s,
    const float* __restrict__ W_ih, const float* __restrict__ W_hh,
    const float* __restrict__ W_sh, const float* __restrict__ bias,
    const float* __restrict__ bias_s, const float* __restrict__ W_fc,
    const float* __restrict__ b_fc, float* __restrict__ d_out)
{
    __shared__ float4 lds_w[18][512];                 // 147,456 B weight tier
    __shared__ __align__(16) float hbuf[HH + FD];     // fp32 [h(256); x_t(32)]
    __shared__ float partials[2][3][HH];              // 6,144 B
    __shared__ float gatec[5][HH];                    // ig, bf, bo, bg, wfc (5,120 B)
    __shared__ float outp[4];
    // total LDS: 159,888 B of 163,840

    const int t = threadIdx.x;
    const int b = blockIdx.x;
    const int kq = t >> 8;            // 0..1, wave-uniform
    const int a  = t & 255;
    const int kbase = kq * KCH;
    const int sbase = kbase + RV + RL;    // first streamed row (92 / 236)

    // ---- tier 1: VGPR-resident weights (rows kbase..kbase+67, all W_hh) ----
    float wv[RV * 3];
#pragma unroll
    for (int r = 0; r < RV; ++r) {
        const float* p = W_hh + (size_t)(kbase + r) * G3;
        wv[3*r+0] = p[a];
        wv[3*r+1] = p[a + 256];
        wv[3*r+2] = p[a + 512];
    }

    // ---- tier 2: LDS-resident weights (rows kbase+68..91, all W_hh) ----
    // per-thread element i = 4j+e in [0,72): local row i/3, gate i%3.
#pragma unroll
    for (int j = 0; j < 18; ++j) {
        float tmp[4];
#pragma unroll
        for (int e = 0; e < 4; ++e) {
            const int i = 4*j + e, r = i / 3, g = i - 3*r;
            tmp[e] = W_hh[(size_t)(kbase + RV + r) * G3 + g*256 + a];
        }
        lds_w[j][t] = make_float4(tmp[0], tmp[1], tmp[2], tmp[3]);
    }

    // ---- gate constants + h0/x0 staging ----
    if (t < HH) {
        float accs = bias_s[t];
        for (int k = 0; k < FS; ++k)
            accs = fmaf(x_s[(size_t)b * FS + k], W_sh[(size_t)k * HH + t], accs);
        gatec[0][t] = sigmoidf_(accs);     // static input gate
        gatec[1][t] = bias[t];
        gatec[2][t] = bias[t + HH];
        gatec[3][t] = bias[t + 2*HH];
        gatec[4][t] = W_fc[t];
        hbuf[t] = 0.f;                      // h0 = 0
    } else if (t < HH + FD) {
        hbuf[t] = x_d[(size_t)b * SS * FD + (t - HH)];   // x_0
    }
    const float bfc = b_fc[0];
    __syncthreads();

    float* __restrict__ out_fc = d_out;                        // [B,S,1]
    float* __restrict__ hn_out = d_out + (size_t)BB * SS;      // [B,S,H]
    float* __restrict__ cn_out = hn_out + (size_t)BB * SS * HH;

    float c_state = 0.f;
    const float4* hq = reinterpret_cast<const float4*>(hbuf);

    for (int s = 0; s < SS; ++s) {
        float acc0 = 0.f, acc1 = 0.f, acc2 = 0.f;

        // prefetch first two streamed quad-blocks (cover L2 latency with tier-1/2 math)
        float va[12], vb[12];
        LOADQ(va, sbase + 0);
        LOADQ(vb, sbase + 4);

        // tier 1: registers (17 quad-blocks = 68 rows)
#pragma unroll
        for (int q = 0; q < 17; ++q) {
            const float4 h4 = hq[kbase/4 + q];
            FMA12(&wv[12*q], h4);
        }
        // tier 2: LDS (6 blocks = 24 rows, 18 b128 reads)
#pragma unroll
        for (int m = 0; m < 6; ++m) {
            const float4 q0 = lds_w[3*m+0][t];
            const float4 q1 = lds_w[3*m+1][t];
            const float4 q2 = lds_w[3*m+2][t];
            const float v[12] = {q0.x,q0.y,q0.z,q0.w, q1.x,q1.y,q1.z,q1.w,
                                 q2.x,q2.y,q2.z,q2.w};
            const float4 h4 = hq[(kbase + RV)/4 + m];
            FMA12(v, h4);
        }
        // tier 3: stream (13 blocks = 52 rows), 2-buffer rolling prefetch
#pragma unroll
        for (int m = 0; m < NQS; ++m) {
            const float4 h4 = hq[sbase/4 + m];
            if (m & 1) {
                FMA12(vb, h4);
                if (m + 2 < NQS) LOADQ(vb, sbase + 4*(m + 2));
            } else {
                FMA12(va, h4);
                if (m + 2 < NQS) LOADQ(va, sbase + 4*(m + 2));
            }
        }

        partials[kq][0][a] = acc0;
        partials[kq][1][a] = acc1;
        partials[kq][2][a] = acc2;
        __syncthreads();

        if (t < HH) {
            const float f = partials[0][0][t] + partials[1][0][t] + gatec[1][t];
            const float o = partials[0][1][t] + partials[1][1][t] + gatec[2][t];
            const float g = partials[0][2][t] + partials[1][2][t] + gatec[3][t];
            const float sf = sigmoidf_(f);
            const float so = sigmoidf_(o);
            const float tg = tanhf_(g);
            c_state = sf * c_state + gatec[0][t] * tg;
            const float tc = tanhf_(c_state);
            const float h1 = so * tc;
            hbuf[t] = h1;
            const size_t oidx = ((size_t)b * SS + s) * HH + t;
            hn_out[oidx] = h1;
            cn_out[oidx] = c_state;
            float p = h1 * gatec[4][t];
            for (int d = 32; d > 0; d >>= 1) p += __shfl_down(p, d);
            if ((t & 63) == 0) outp[t >> 6] = p;
        } else if (t < HH + FD) {
            const int sn = (s + 1 < SS) ? (s + 1) : s;
            hbuf[t] = x_d[(size_t)b * SS * FD + (size_t)sn * FD + (t - HH)];
        }
        __syncthreads();
        if (t == 0) {
            out_fc[(size_t)b * SS + s] = outp[0] + outp[1] + outp[2] + outp[3] + bfc;
        }
    }
}

extern "C" void kernel_launch(void* const* d_in, const int* in_sizes, int n_in,
                              void* d_out, int out_size, void* d_ws, size_t ws_size,
                              hipStream_t stream) {
    const float* x_d    = (const float*)d_in[0];
    const float* x_s    = (const float*)d_in[1];
    const float* W_ih   = (const float*)d_in[2];
    const float* W_hh   = (const float*)d_in[3];
    const float* W_sh   = (const float*)d_in[4];
    const float* bias   = (const float*)d_in[5];
    const float* bias_s = (const float*)d_in[6];
    const float* W_fc   = (const float*)d_in[7];
    const float* b_fc   = (const float*)d_in[8];

    ealstm_kernel<<<dim3(BB), dim3(512), 0, stream>>>(
        x_d, x_s, W_ih, W_hh, W_sh, bias, bias_s, W_fc, b_fc, (float*)d_out);
}